// Round 2
// baseline (629.991 us; speedup 1.0000x reference)
//
#include <hip/hip_runtime.h>

#define TILE 128
#define VSZ  192   // floats of per-view data in workspace (186 used, padded)

// ---------------- SH basis (degree 4, 25 components), double ----------------
__device__ void sh_basis25_d(double x, double y, double z, double* Y) {
    double x2 = x * x, y2 = y * y, z2 = z * z;
    Y[0]  = 0.2820947918;
    Y[1]  = 0.4886025119 * y;
    Y[2]  = 0.4886025119 * z;
    Y[3]  = 0.4886025119 * x;
    Y[4]  = 1.0925484306 * x * y;
    Y[5]  = 1.0925484306 * y * z;
    Y[6]  = 0.3153915653 * (3.0 * z2 - 1.0);
    Y[7]  = 1.0925484306 * x * z;
    Y[8]  = 0.5462742153 * (x2 - y2);
    Y[9]  = 0.5900435899 * y * (3.0 * x2 - y2);
    Y[10] = 2.8906114426 * x * y * z;
    Y[11] = 0.4570457995 * y * (5.0 * z2 - 1.0);
    Y[12] = 0.3731763326 * z * (5.0 * z2 - 3.0);
    Y[13] = 0.4570457995 * x * (5.0 * z2 - 1.0);
    Y[14] = 1.4453057213 * z * (x2 - y2);
    Y[15] = 0.5900435899 * x * (x2 - 3.0 * y2);
    Y[16] = 2.5033429418 * x * y * (x2 - y2);
    Y[17] = 1.7701307698 * y * z * (3.0 * x2 - y2);
    Y[18] = 0.9461746958 * x * y * (7.0 * z2 - 1.0);
    Y[19] = 0.6690465436 * y * z * (7.0 * z2 - 3.0);
    Y[20] = 0.1057855469 * (35.0 * z2 * z2 - 30.0 * z2 + 3.0);
    Y[21] = 0.6690465436 * x * z * (7.0 * z2 - 3.0);
    Y[22] = 0.4730873479 * (x2 - y2) * (7.0 * z2 - 1.0);
    Y[23] = 1.7701307698 * x * z * (x2 - 3.0 * y2);
    Y[24] = 0.6258357354 * (x2 * x2 - 6.0 * x2 * y2 + y2 * y2);
}

// Gauss-Jordan inverse with partial pivoting, n <= 9, double. A destroyed.
__device__ void gj_invert_d(double* A, double* X, int n) {
    for (int i = 0; i < n; i++)
        for (int j = 0; j < n; j++) X[i * n + j] = (i == j) ? 1.0 : 0.0;
    for (int c = 0; c < n; c++) {
        int p = c; double best = fabs(A[c * n + c]);
        for (int r = c + 1; r < n; r++) {
            double v = fabs(A[r * n + c]);
            if (v > best) { best = v; p = r; }
        }
        if (p != c) {
            for (int j = 0; j < n; j++) {
                double tA = A[c * n + j]; A[c * n + j] = A[p * n + j]; A[p * n + j] = tA;
                double tX = X[c * n + j]; X[c * n + j] = X[p * n + j]; X[p * n + j] = tX;
            }
        }
        double inv = 1.0 / A[c * n + c];
        for (int j = 0; j < n; j++) { A[c * n + j] *= inv; X[c * n + j] *= inv; }
        for (int r = 0; r < n; r++) {
            if (r == c) continue;
            double f = A[r * n + c];
            if (f == 0.0) continue;
            for (int j = 0; j < n; j++) {
                A[r * n + j] -= f * A[c * n + j];
                X[r * n + j] -= f * X[c * n + j];
            }
        }
    }
}

// Per-view data layout (floats):
// [0:9)   R_c2w row-major
// [9:12)  cam_o
// [12:21) Kinv row-major
// [21]    scale_adj
// [22:31) D1 (3x3)   [31:56) D2 (5x5)   [56:105) D3 (7x7)   [105:186) D4 (9x9)
__global__ void setup_kernel(const float* __restrict__ ext,
                             const float* __restrict__ intr,
                             const int* __restrict__ ph,
                             const int* __restrict__ pw,
                             float* __restrict__ vdg) {
    if (threadIdx.x != 0) return;
    int bv = blockIdx.x;
    const float* E = ext + bv * 16;
    const float* K = intr + bv * 9;
    float* o = vdg + bv * VSZ;

    float Rw2c[3][3], Rc2w[3][3], t[3];
    for (int i = 0; i < 3; i++) {
        for (int j = 0; j < 3; j++) Rw2c[i][j] = E[i * 4 + j];
        t[i] = E[i * 4 + 3];
    }
    for (int i = 0; i < 3; i++)
        for (int j = 0; j < 3; j++) Rc2w[i][j] = Rw2c[j][i];
    for (int i = 0; i < 3; i++)
        for (int j = 0; j < 3; j++) o[i * 3 + j] = Rc2w[i][j];
    for (int i = 0; i < 3; i++) {
        float s = 0.f;
        for (int j = 0; j < 3; j++) s += Rc2w[i][j] * t[j];
        o[9 + i] = -s;
    }
    // Kinv (full 3x3 adjugate)
    float a = K[0], b = K[1], c = K[2], d = K[3], e = K[4], f = K[5],
          g = K[6], h = K[7], ii = K[8];
    float det = a * (e * ii - f * h) - b * (d * ii - f * g) + c * (d * h - e * g);
    float id = 1.0f / det;
    o[12 + 0] = (e * ii - f * h) * id; o[12 + 1] = (c * h - b * ii) * id; o[12 + 2] = (b * f - c * e) * id;
    o[12 + 3] = (f * g - d * ii) * id; o[12 + 4] = (a * ii - c * g) * id; o[12 + 5] = (c * d - a * f) * id;
    o[12 + 6] = (d * h - e * g) * id; o[12 + 7] = (b * g - a * h) * id; o[12 + 8] = (a * e - b * d) * id;
    // scale_adj = 0.1 * sum_ij K2inv[i][j] * ps[j]
    float det2 = a * e - b * d;
    float i00 = e / det2, i01 = -b / det2, i10 = -d / det2, i11 = a / det2;
    float ps0 = 1.0f / (float)(*pw), ps1 = 1.0f / (float)(*ph);
    o[21] = 0.1f * ((i00 + i10) * ps0 + (i01 + i11) * ps1);

    // --- Wigner D per band, in double, with provably well-conditioned samples.
    // Single ring at z0=0.5, 2l+1 equally spaced phases: B = DFT * diag(g_m),
    // orthogonal columns (cond(B) ~ 3-5), all g_m(0.5) != 0 for l<=4.
    double Rd[3][3];
    for (int i = 0; i < 3; i++)
        for (int j = 0; j < 3; j++) Rd[i][j] = (double)Rw2c[i][j];

    const int dofs[5] = {0, 22, 31, 56, 105};
    const double z0 = 0.5, r0 = 0.86602540378443864676;  // sqrt(3)/2
    const double TWO_PI = 6.2831853071795864769;
    for (int l = 1; l <= 4; l++) {
        int n = 2 * l + 1, lo = l * l;
        double S[9][3];
        for (int k = 0; k < n; k++) {
            double phs = 0.4 + TWO_PI * (double)k / (double)n;
            S[k][0] = r0 * cos(phs);
            S[k][1] = r0 * sin(phs);
            S[k][2] = z0;
        }
        double Bm[81], Binv[81], Yr[81], Y[25];
        for (int s = 0; s < n; s++) {
            sh_basis25_d(S[s][0], S[s][1], S[s][2], Y);
            for (int k = 0; k < n; k++) Bm[s * n + k] = Y[lo + k];
            // drot = R_w2c @ s
            double dx = Rd[0][0] * S[s][0] + Rd[0][1] * S[s][1] + Rd[0][2] * S[s][2];
            double dy = Rd[1][0] * S[s][0] + Rd[1][1] * S[s][1] + Rd[1][2] * S[s][2];
            double dz = Rd[2][0] * S[s][0] + Rd[2][1] * S[s][1] + Rd[2][2] * S[s][2];
            sh_basis25_d(dx, dy, dz, Y);
            for (int k = 0; k < n; k++) Yr[s * n + k] = Y[lo + k];
        }
        gj_invert_d(Bm, Binv, n);
        float* D = o + dofs[l];
        for (int m = 0; m < n; m++)
            for (int k = 0; k < n; k++) {
                double acc = 0.0;
                for (int s = 0; s < n; s++) acc += Yr[s * n + k] * Binv[m * n + s];
                D[m * n + k] = (float)acc;
            }
    }
}

template <int NB>
__device__ __forceinline__ void apply_D(const float* __restrict__ D,
                                        const float* __restrict__ si,
                                        float* __restrict__ so) {
#pragma unroll
    for (int m = 0; m < NB; m++) {
        float acc = 0.f;
#pragma unroll
        for (int k = 0; k < NB; k++) acc += D[m * NB + k] * si[k];
        so[m] = acc;
    }
}

__global__ __launch_bounds__(TILE) void adapter_kernel(
    const float* __restrict__ pg, const float* __restrict__ pc,
    const float* __restrict__ ops, const float* __restrict__ deps,
    const float* __restrict__ vdg, float* __restrict__ out,
    int R, long long N)
{
    __shared__ float vd[VSZ];
    __shared__ float tile[TILE * 82];
    int bv = blockIdx.y;
    long long base = (long long)bv * R + (long long)blockIdx.x * TILE;
    int cnt = R - blockIdx.x * TILE;
    if (cnt > TILE) cnt = TILE;

    for (int i = threadIdx.x; i < 186; i += TILE) vd[i] = vdg[bv * VSZ + i];

    const float* src = pg + base * 82;
    if (cnt == TILE && ((base * 82) & 3) == 0) {
        const float4* s4 = (const float4*)src;
        float4* d4 = (float4*)tile;
        for (int i = threadIdx.x; i < TILE * 82 / 4; i += TILE) d4[i] = s4[i];
    } else {
        for (int i = threadIdx.x; i < cnt * 82; i += TILE) tile[i] = src[i];
    }
    __syncthreads();

    int t = threadIdx.x;
    if (t >= cnt) return;
    const float* gp = tile + t * 82;
    long long g = base + t;

    float depth = deps[g];
    float opac  = ops[g];
    float px = pc[2 * g], py = pc[2 * g + 1];

    // --- scales ---
    float sadj = vd[21];
    float sc[3];
#pragma unroll
    for (int i = 0; i < 3; i++) {
        float sg = 1.0f / (1.0f + expf(-gp[i]));
        sc[i] = (0.01f + 99.99f * sg) * depth * sadj;
    }

    // --- quats ---
    float qw = gp[3], qx = gp[4], qy = gp[5], qz = gp[6];
    float qn = rsqrtf(qw * qw + qx * qx + qy * qy + qz * qz);
    qw *= qn; qx *= qn; qy *= qn; qz *= qn;
    float Rq[3][3];
    Rq[0][0] = 1.f - 2.f * (qy * qy + qz * qz);
    Rq[0][1] = 2.f * (qx * qy - qw * qz);
    Rq[0][2] = 2.f * (qx * qz + qw * qy);
    Rq[1][0] = 2.f * (qx * qy + qw * qz);
    Rq[1][1] = 1.f - 2.f * (qx * qx + qz * qz);
    Rq[1][2] = 2.f * (qy * qz - qw * qx);
    Rq[2][0] = 2.f * (qx * qz - qw * qy);
    Rq[2][1] = 2.f * (qy * qz + qw * qx);
    Rq[2][2] = 1.f - 2.f * (qx * qx + qy * qy);

    float Rc[3][3];
#pragma unroll
    for (int i = 0; i < 3; i++)
#pragma unroll
        for (int j = 0; j < 3; j++) Rc[i][j] = vd[i * 3 + j];

    // A = Rc2w @ Rq ; cov = A diag(s^2) A^T
    float A[3][3];
#pragma unroll
    for (int i = 0; i < 3; i++)
#pragma unroll
        for (int k = 0; k < 3; k++)
            A[i][k] = Rc[i][0] * Rq[0][k] + Rc[i][1] * Rq[1][k] + Rc[i][2] * Rq[2][k];
    float s2[3] = {sc[0] * sc[0], sc[1] * sc[1], sc[2] * sc[2]};
    float cov[3][3];
#pragma unroll
    for (int i = 0; i < 3; i++)
#pragma unroll
        for (int j = 0; j < 3; j++)
            cov[i][j] = A[i][0] * s2[0] * A[j][0] + A[i][1] * s2[1] * A[j][1] + A[i][2] * s2[2] * A[j][2];

    // --- ray / means ---
    float dx = vd[12] * px + vd[13] * py + vd[14];
    float dy = vd[15] * px + vd[16] * py + vd[17];
    float dz = vd[18] * px + vd[19] * py + vd[20];
    float dn = rsqrtf(dx * dx + dy * dy + dz * dz);
    dx *= dn; dy *= dn; dz *= dn;
    float rdx = Rc[0][0] * dx + Rc[0][1] * dy + Rc[0][2] * dz;
    float rdy = Rc[1][0] * dx + Rc[1][1] * dy + Rc[1][2] * dz;
    float rdz = Rc[2][0] * dx + Rc[2][1] * dy + Rc[2][2] * dz;
    float mex = vd[9]  + rdx * depth;
    float mey = vd[10] + rdy * depth;
    float mez = vd[11] + rdz * depth;

    // --- stores ---
    float* om  = out;
    float* os  = out + 3 * N;
    float* oc  = out + 6 * N;
    float* oq  = out + 15 * N;
    float* oo  = out + 19 * N;
    float* osh = out + 20 * N;

    om[3 * g + 0] = mex; om[3 * g + 1] = mey; om[3 * g + 2] = mez;
    os[3 * g + 0] = sc[0]; os[3 * g + 1] = sc[1]; os[3 * g + 2] = sc[2];
#pragma unroll
    for (int i = 0; i < 3; i++)
#pragma unroll
        for (int j = 0; j < 3; j++) oc[9 * g + i * 3 + j] = cov[i][j];
    oq[4 * g + 0] = qw; oq[4 * g + 1] = qx; oq[4 * g + 2] = qy; oq[4 * g + 3] = qz;
    oo[g] = opac;

    // --- SH rotation ---
    const float* shin = gp + 7;
    float* shout = osh + 75 * g;
#pragma unroll
    for (int ch = 0; ch < 3; ch++) {
        const float* si = shin + 25 * ch;
        float* so = shout + 25 * ch;
        so[0] = si[0];
        apply_D<3>(vd + 22,  si + 1,  so + 1);
        apply_D<5>(vd + 31,  si + 4,  so + 4);
        apply_D<7>(vd + 56,  si + 9,  so + 9);
        apply_D<9>(vd + 105, si + 16, so + 16);
    }
}

extern "C" void kernel_launch(void* const* d_in, const int* in_sizes, int n_in,
                              void* d_out, int out_size, void* d_ws, size_t ws_size,
                              hipStream_t stream) {
    const float* pg   = (const float*)d_in[0];
    const float* pc   = (const float*)d_in[1];
    const float* ext  = (const float*)d_in[2];
    const float* intr = (const float*)d_in[3];
    const float* ops  = (const float*)d_in[4];
    const float* dep  = (const float*)d_in[5];
    const int*   ph   = (const int*)d_in[6];
    const int*   pw   = (const int*)d_in[7];

    int BV = in_sizes[2] / 16;               // extrinsics B*V*4*4
    long long N = (long long)in_sizes[4];    // opacities B*V*R
    int R = (int)(N / BV);

    float* vd = (float*)d_ws;
    setup_kernel<<<BV, 64, 0, stream>>>(ext, intr, ph, pw, vd);

    dim3 grid((R + TILE - 1) / TILE, BV);
    adapter_kernel<<<grid, TILE, 0, stream>>>(pg, pc, ops, dep, vd, (float*)d_out, R, N);
}

// Round 3
// 165.005 us; speedup vs baseline: 3.8180x; 3.8180x over previous
//
#include <hip/hip_runtime.h>

#define TILE 128
#define VSZ  192   // floats of per-view data in workspace (186 used, padded)

// ---------------- SH basis (degree 4, 25 components), float ----------------
__device__ __forceinline__ void sh_basis25(float x, float y, float z, float* Y) {
    float x2 = x * x, y2 = y * y, z2 = z * z;
    Y[0]  = 0.2820947918f;
    Y[1]  = 0.4886025119f * y;
    Y[2]  = 0.4886025119f * z;
    Y[3]  = 0.4886025119f * x;
    Y[4]  = 1.0925484306f * x * y;
    Y[5]  = 1.0925484306f * y * z;
    Y[6]  = 0.3153915653f * (3.0f * z2 - 1.0f);
    Y[7]  = 1.0925484306f * x * z;
    Y[8]  = 0.5462742153f * (x2 - y2);
    Y[9]  = 0.5900435899f * y * (3.0f * x2 - y2);
    Y[10] = 2.8906114426f * x * y * z;
    Y[11] = 0.4570457995f * y * (5.0f * z2 - 1.0f);
    Y[12] = 0.3731763326f * z * (5.0f * z2 - 3.0f);
    Y[13] = 0.4570457995f * x * (5.0f * z2 - 1.0f);
    Y[14] = 1.4453057213f * z * (x2 - y2);
    Y[15] = 0.5900435899f * x * (x2 - 3.0f * y2);
    Y[16] = 2.5033429418f * x * y * (x2 - y2);
    Y[17] = 1.7701307698f * y * z * (3.0f * x2 - y2);
    Y[18] = 0.9461746958f * x * y * (7.0f * z2 - 1.0f);
    Y[19] = 0.6690465436f * y * z * (7.0f * z2 - 3.0f);
    Y[20] = 0.1057855469f * (35.0f * z2 * z2 - 30.0f * z2 + 3.0f);
    Y[21] = 0.6690465436f * x * z * (7.0f * z2 - 3.0f);
    Y[22] = 0.4730873479f * (x2 - y2) * (7.0f * z2 - 1.0f);
    Y[23] = 1.7701307698f * x * z * (x2 - 3.0f * y2);
    Y[24] = 0.6258357354f * (x2 * x2 - 6.0f * x2 * y2 + y2 * y2);
}

// Per-view data layout (floats):
// [0:9)   R_c2w row-major
// [9:12)  cam_o
// [12:21) Kinv row-major
// [21]    scale_adj
// [22:31) D1 (3x3)   [31:56) D2 (5x5)   [56:105) D3 (7x7)   [105:186) D4 (9x9)
//
// Ring sample set per band l: 2l+1 equally spaced phases at z0=0.5.
// In-band real SH on the ring are g_m * {1, cos(m phi), sin(m phi)} with
// freq <= l < n  ->  discrete trig orthogonality is EXACT, so
// Binv[m,s] = B[s,m] / sum_s' B[s',m]^2  (no matrix inversion needed).
// D[m,k] = sum_s Y_k(Rw2c . dir_s) * Binv[m,s].
//
// One block (64 threads) per view; small arrays in LDS; all fp32.
__global__ __launch_bounds__(64) void setup_kernel(
        const float* __restrict__ ext,
        const float* __restrict__ intr,
        const int* __restrict__ ph,
        const int* __restrict__ pw,
        float* __restrict__ vdg) {
    __shared__ float Bs[24][9];     // unrotated basis rows (sample-major)
    __shared__ float Yrs[24][9];    // rotated basis rows
    __shared__ float normInv[24];   // per-(l,m) 1/norm

    int bv = blockIdx.x;
    int tid = threadIdx.x;
    const float* E = ext + bv * 16;
    const float* K = intr + bv * 9;
    float* o = vdg + bv * VSZ;

    const float z0 = 0.5f, r0 = 0.8660254037844386f;  // sqrt(3)/2
    const float TWO_PI = 6.283185307179586f;
    // band boundaries in the flat 24-sample space: l=1:[0,3) l=2:[3,8) l=3:[8,15) l=4:[15,24)
    // same boundaries index the 24 (l,m) pairs.

    // ---- Stage A: threads 0..23 evaluate one sample each ----
    if (tid < 24) {
        int l, base;
        if      (tid < 3)  { l = 1; base = 0;  }
        else if (tid < 8)  { l = 2; base = 3;  }
        else if (tid < 15) { l = 3; base = 8;  }
        else               { l = 4; base = 15; }
        int n  = 2 * l + 1;
        int si = tid - base;
        int lo = l * l;
        float phs = 0.4f + TWO_PI * (float)si / (float)n;
        float sx = r0 * cosf(phs), sy = r0 * sinf(phs), sz = z0;
        float Y[25];
        sh_basis25(sx, sy, sz, Y);
        for (int k = 0; k < n; k++) Bs[tid][k] = Y[lo + k];
        // rotated dir = Rw2c . s   (Rw2c = E[:3,:3] row-major)
        float dx = E[0] * sx + E[1] * sy + E[2]  * sz;
        float dy = E[4] * sx + E[5] * sy + E[6]  * sz;
        float dz = E[8] * sx + E[9] * sy + E[10] * sz;
        sh_basis25(dx, dy, dz, Y);
        for (int k = 0; k < n; k++) Yrs[tid][k] = Y[lo + k];
    }
    __syncthreads();

    // ---- Stage B: threads 0..23 compute 1/norm for one (l,m) pair each ----
    if (tid < 24) {
        int l, base;
        if      (tid < 3)  { l = 1; base = 0;  }
        else if (tid < 8)  { l = 2; base = 3;  }
        else if (tid < 15) { l = 3; base = 8;  }
        else               { l = 4; base = 15; }
        int n = 2 * l + 1;
        int m = tid - base;
        float acc = 0.f;
        for (int s = 0; s < n; s++) { float v = Bs[base + s][m]; acc += v * v; }
        normInv[tid] = 1.0f / acc;
    }
    __syncthreads();

    // ---- Stage C: 164 D-entries across 64 threads ----
    // band entry-offsets: l=1:0..9, l=2:9..34, l=3:34..83, l=4:83..164
    const int dofs[5] = {0, 22, 31, 56, 105};
    for (int e = tid; e < 164; e += 64) {
        int l, ebase, sbase;
        if      (e < 9)  { l = 1; ebase = 0;  sbase = 0;  }
        else if (e < 34) { l = 2; ebase = 9;  sbase = 3;  }
        else if (e < 83) { l = 3; ebase = 34; sbase = 8;  }
        else             { l = 4; ebase = 83; sbase = 15; }
        int n = 2 * l + 1;
        int el = e - ebase;
        int m = el / n, k = el % n;
        float acc = 0.f;
        for (int s = 0; s < n; s++) acc += Yrs[sbase + s][k] * Bs[sbase + s][m];
        o[dofs[l] + m * n + k] = acc * normInv[sbase + m];
    }

    // ---- misc per-view data on thread 0 ----
    if (tid == 0) {
        float Rw2c[3][3], Rc2w[3][3], t[3];
        for (int i = 0; i < 3; i++) {
            for (int j = 0; j < 3; j++) Rw2c[i][j] = E[i * 4 + j];
            t[i] = E[i * 4 + 3];
        }
        for (int i = 0; i < 3; i++)
            for (int j = 0; j < 3; j++) Rc2w[i][j] = Rw2c[j][i];
        for (int i = 0; i < 3; i++)
            for (int j = 0; j < 3; j++) o[i * 3 + j] = Rc2w[i][j];
        for (int i = 0; i < 3; i++) {
            float s = 0.f;
            for (int j = 0; j < 3; j++) s += Rc2w[i][j] * t[j];
            o[9 + i] = -s;
        }
        // Kinv (full 3x3 adjugate)
        float a = K[0], b = K[1], c = K[2], d = K[3], e = K[4], f = K[5],
              g = K[6], h = K[7], ii = K[8];
        float det = a * (e * ii - f * h) - b * (d * ii - f * g) + c * (d * h - e * g);
        float id = 1.0f / det;
        o[12 + 0] = (e * ii - f * h) * id; o[12 + 1] = (c * h - b * ii) * id; o[12 + 2] = (b * f - c * e) * id;
        o[12 + 3] = (f * g - d * ii) * id; o[12 + 4] = (a * ii - c * g) * id; o[12 + 5] = (c * d - a * f) * id;
        o[12 + 6] = (d * h - e * g) * id; o[12 + 7] = (b * g - a * h) * id; o[12 + 8] = (a * e - b * d) * id;
        // scale_adj = 0.1 * sum_ij K2inv[i][j] * ps[j]
        float det2 = a * e - b * d;
        float i00 = e / det2, i01 = -b / det2, i10 = -d / det2, i11 = a / det2;
        float ps0 = 1.0f / (float)(*pw), ps1 = 1.0f / (float)(*ph);
        o[21] = 0.1f * ((i00 + i10) * ps0 + (i01 + i11) * ps1);
    }
}

template <int NB>
__device__ __forceinline__ void apply_D(const float* __restrict__ D,
                                        const float* __restrict__ si,
                                        float* __restrict__ so) {
#pragma unroll
    for (int m = 0; m < NB; m++) {
        float acc = 0.f;
#pragma unroll
        for (int k = 0; k < NB; k++) acc += D[m * NB + k] * si[k];
        so[m] = acc;
    }
}

__global__ __launch_bounds__(TILE) void adapter_kernel(
    const float* __restrict__ pg, const float* __restrict__ pc,
    const float* __restrict__ ops, const float* __restrict__ deps,
    const float* __restrict__ vdg, float* __restrict__ out,
    int R, long long N)
{
    __shared__ float vd[VSZ];
    __shared__ float tile[TILE * 82];
    int bv = blockIdx.y;
    long long base = (long long)bv * R + (long long)blockIdx.x * TILE;
    int cnt = R - blockIdx.x * TILE;
    if (cnt > TILE) cnt = TILE;

    for (int i = threadIdx.x; i < 186; i += TILE) vd[i] = vdg[bv * VSZ + i];

    const float* src = pg + base * 82;
    if (cnt == TILE && ((base * 82) & 3) == 0) {
        const float4* s4 = (const float4*)src;
        float4* d4 = (float4*)tile;
        for (int i = threadIdx.x; i < TILE * 82 / 4; i += TILE) d4[i] = s4[i];
    } else {
        for (int i = threadIdx.x; i < cnt * 82; i += TILE) tile[i] = src[i];
    }
    __syncthreads();

    int t = threadIdx.x;
    if (t >= cnt) return;
    const float* gp = tile + t * 82;
    long long g = base + t;

    float depth = deps[g];
    float opac  = ops[g];
    float px = pc[2 * g], py = pc[2 * g + 1];

    // --- scales ---
    float sadj = vd[21];
    float sc[3];
#pragma unroll
    for (int i = 0; i < 3; i++) {
        float sg = 1.0f / (1.0f + expf(-gp[i]));
        sc[i] = (0.01f + 99.99f * sg) * depth * sadj;
    }

    // --- quats ---
    float qw = gp[3], qx = gp[4], qy = gp[5], qz = gp[6];
    float qn = rsqrtf(qw * qw + qx * qx + qy * qy + qz * qz);
    qw *= qn; qx *= qn; qy *= qn; qz *= qn;
    float Rq[3][3];
    Rq[0][0] = 1.f - 2.f * (qy * qy + qz * qz);
    Rq[0][1] = 2.f * (qx * qy - qw * qz);
    Rq[0][2] = 2.f * (qx * qz + qw * qy);
    Rq[1][0] = 2.f * (qx * qy + qw * qz);
    Rq[1][1] = 1.f - 2.f * (qx * qx + qz * qz);
    Rq[1][2] = 2.f * (qy * qz - qw * qx);
    Rq[2][0] = 2.f * (qx * qz - qw * qy);
    Rq[2][1] = 2.f * (qy * qz + qw * qx);
    Rq[2][2] = 1.f - 2.f * (qx * qx + qy * qy);

    float Rc[3][3];
#pragma unroll
    for (int i = 0; i < 3; i++)
#pragma unroll
        for (int j = 0; j < 3; j++) Rc[i][j] = vd[i * 3 + j];

    // A = Rc2w @ Rq ; cov = A diag(s^2) A^T
    float A[3][3];
#pragma unroll
    for (int i = 0; i < 3; i++)
#pragma unroll
        for (int k = 0; k < 3; k++)
            A[i][k] = Rc[i][0] * Rq[0][k] + Rc[i][1] * Rq[1][k] + Rc[i][2] * Rq[2][k];
    float s2[3] = {sc[0] * sc[0], sc[1] * sc[1], sc[2] * sc[2]};
    float cov[3][3];
#pragma unroll
    for (int i = 0; i < 3; i++)
#pragma unroll
        for (int j = 0; j < 3; j++)
            cov[i][j] = A[i][0] * s2[0] * A[j][0] + A[i][1] * s2[1] * A[j][1] + A[i][2] * s2[2] * A[j][2];

    // --- ray / means ---
    float dx = vd[12] * px + vd[13] * py + vd[14];
    float dy = vd[15] * px + vd[16] * py + vd[17];
    float dz = vd[18] * px + vd[19] * py + vd[20];
    float dn = rsqrtf(dx * dx + dy * dy + dz * dz);
    dx *= dn; dy *= dn; dz *= dn;
    float rdx = Rc[0][0] * dx + Rc[0][1] * dy + Rc[0][2] * dz;
    float rdy = Rc[1][0] * dx + Rc[1][1] * dy + Rc[1][2] * dz;
    float rdz = Rc[2][0] * dx + Rc[2][1] * dy + Rc[2][2] * dz;
    float mex = vd[9]  + rdx * depth;
    float mey = vd[10] + rdy * depth;
    float mez = vd[11] + rdz * depth;

    // --- stores ---
    float* om  = out;
    float* os  = out + 3 * N;
    float* oc  = out + 6 * N;
    float* oq  = out + 15 * N;
    float* oo  = out + 19 * N;
    float* osh = out + 20 * N;

    om[3 * g + 0] = mex; om[3 * g + 1] = mey; om[3 * g + 2] = mez;
    os[3 * g + 0] = sc[0]; os[3 * g + 1] = sc[1]; os[3 * g + 2] = sc[2];
#pragma unroll
    for (int i = 0; i < 3; i++)
#pragma unroll
        for (int j = 0; j < 3; j++) oc[9 * g + i * 3 + j] = cov[i][j];
    oq[4 * g + 0] = qw; oq[4 * g + 1] = qx; oq[4 * g + 2] = qy; oq[4 * g + 3] = qz;
    oo[g] = opac;

    // --- SH rotation ---
    const float* shin = gp + 7;
    float* shout = osh + 75 * g;
#pragma unroll
    for (int ch = 0; ch < 3; ch++) {
        const float* si = shin + 25 * ch;
        float* so = shout + 25 * ch;
        so[0] = si[0];
        apply_D<3>(vd + 22,  si + 1,  so + 1);
        apply_D<5>(vd + 31,  si + 4,  so + 4);
        apply_D<7>(vd + 56,  si + 9,  so + 9);
        apply_D<9>(vd + 105, si + 16, so + 16);
    }
}

extern "C" void kernel_launch(void* const* d_in, const int* in_sizes, int n_in,
                              void* d_out, int out_size, void* d_ws, size_t ws_size,
                              hipStream_t stream) {
    const float* pg   = (const float*)d_in[0];
    const float* pc   = (const float*)d_in[1];
    const float* ext  = (const float*)d_in[2];
    const float* intr = (const float*)d_in[3];
    const float* ops  = (const float*)d_in[4];
    const float* dep  = (const float*)d_in[5];
    const int*   ph   = (const int*)d_in[6];
    const int*   pw   = (const int*)d_in[7];

    int BV = in_sizes[2] / 16;               // extrinsics B*V*4*4
    long long N = (long long)in_sizes[4];    // opacities B*V*R
    int R = (int)(N / BV);

    float* vd = (float*)d_ws;
    setup_kernel<<<BV, 64, 0, stream>>>(ext, intr, ph, pw, vd);

    dim3 grid((R + TILE - 1) / TILE, BV);
    adapter_kernel<<<grid, TILE, 0, stream>>>(pg, pc, ops, dep, vd, (float*)d_out, R, N);
}